// Round 19
// baseline (27.024 us; speedup 1.0000x reference)
//
#include <hip/hip_runtime.h>
#include <hip/hip_bf16.h>

#define HWC 16384      // H*W
#define WD  128
#define NC  64
#define EPSV 1e-6f

typedef __attribute__((ext_vector_type(8))) short bf16x8;
typedef __attribute__((ext_vector_type(4))) float f32x4;
typedef __attribute__((ext_vector_type(2))) float f32x2;
typedef __attribute__((ext_vector_type(4))) unsigned int u32x4;

// f32 pair -> packed bf16 (RNE, v_cvt_pk_bf16_f32)
__device__ __forceinline__ unsigned cvt2(float a, float b) {
  union { __hip_bfloat162 h; unsigned u; } r;
  r.h = __float22bfloat162_rn(make_float2(a, b));
  return r.u;
}
__device__ __forceinline__ float bfLo(unsigned pk) { return __builtin_bit_cast(float, pk << 16); }
__device__ __forceinline__ float bfHi(unsigned pk) { return __builtin_bit_cast(float, pk & 0xFFFF0000u); }
__device__ __forceinline__ f32x2 up2(unsigned w) {
  f32x2 r; r[0] = bfLo(w); r[1] = bfHi(w); return r;
}
__device__ __forceinline__ float frcp(float x) { return __builtin_amdgcn_rcpf(x); }
// XOR swizzle for 128-B-row bf16 tiles.
__device__ __forceinline__ int swz(int row, int colbytes) {
  return ((row << 7) + colbytes) ^ ((row & 7) << 4);
}
__device__ __forceinline__ bf16x8 pack8(float4 a, float4 b) {
  union { unsigned u[4]; bf16x8 v; } r;
  r.u[0] = cvt2(a.x, a.y); r.u[1] = cvt2(a.z, a.w);
  r.u[2] = cvt2(b.x, b.y); r.u[3] = cvt2(b.z, b.w);
  return r.v;
}

// stage one tap row (36 sites x 64 ch, clamped col w0-2+s) into buf
__device__ __forceinline__ void stage_row(const float* __restrict__ xr, int w0,
                                          int t, unsigned short* buf) {
  {
    const int s = t & 31, cg = t >> 5;
    int col = w0 - 2 + s; if (col < 0) col = 0;        // upper clamp impossible (<=125)
    const float* p = xr + col;
    float f[8];
#pragma unroll
    for (int u = 0; u < 8; ++u) f[u] = p[(size_t)(cg * 8 + u) * HWC];
    u32x4 v;
    v[0] = cvt2(f[0], f[1]); v[1] = cvt2(f[2], f[3]);
    v[2] = cvt2(f[4], f[5]); v[3] = cvt2(f[6], f[7]);
    *(u32x4*)((char*)buf + swz(s, cg * 16)) = v;
  }
  if (t < 32) {   // extra sites 32..35
    const int s = 32 + (t & 3), cg = t >> 2;
    int col = w0 - 2 + s; if (col > 127) col = 127;    // lower clamp impossible (>=30)
    const float* p = xr + col;
    float f[8];
#pragma unroll
    for (int u = 0; u < 8; ++u) f[u] = p[(size_t)(cg * 8 + u) * HWC];
    u32x4 v;
    v[0] = cvt2(f[0], f[1]); v[1] = cvt2(f[2], f[3]);
    v[2] = cvt2(f[4], f[5]); v[3] = cvt2(f[6], f[7]);
    *(u32x4*)((char*)buf + swz(s, cg * 16)) = v;
  }
}

// Fully fused head->NMF->tail, 4 output rows per block (8-row tap window
// shared -> 31% less stage+head). 256 thr = 4 waves, 32-px segment.
// grid 512 (b, yq, seg). Packed f32x2 NMF, shfl butterfly, fast rcp.
__global__ __launch_bounds__(256) void k_fused(const float* __restrict__ x,
                                               const float* __restrict__ Wh,
                                               const float* __restrict__ Wt,
                                               float* __restrict__ out) {
  __shared__ __align__(16) char smem[49152];
  unsigned short* bufA = (unsigned short*)smem;          // 48 sites x 128B = 6144
  unsigned short* bufB = (unsigned short*)(smem + 6144); // 6144
  unsigned short* hl = (unsigned short*)(smem + 12288);  // [288 sites][64 o], 36864
  unsigned short* uvb = (unsigned short*)smem;           // overlay bufA after heads

  const int t = threadIdx.x, lane = t & 63, wv = t >> 6;
  const int bid0 = blockIdx.x;
  const int bidS = ((bid0 & 7) << 6) | (bid0 >> 3);  // XCD swizzle, bijective (512%8==0)
  const int seg = bidS & 3, yq = (bidS >> 2) & 31, b = bidS >> 7;
  const int w0 = seg << 5;
  const int y0 = yq << 2;
  const int l15 = lane & 15, kg = lane >> 4;
  const int mrow = (wv << 4) + l15;   // wave = M-tile

  int gyw[8];
#pragma unroll
  for (int i = 0; i < 8; ++i) {
    int yy = y0 - 2 + i;
    gyw[i] = yy < 0 ? 0 : (yy > 127 ? 127 : yy);
  }

  const float* xb = x + (size_t)b * (NC * HWC);

  // ---- head A fragments from global Wh (L2-resident) ----
  bf16x8 ha0, ha1;
  {
    const float* wr = Wh + mrow * 64 + kg * 8;
    ha0 = pack8(*(const float4*)wr, *(const float4*)(wr + 4));
    ha1 = pack8(*(const float4*)(wr + 32), *(const float4*)(wr + 36));
  }

  // ==== stage+head pipeline over the 8-row tap window (dbuf xt) ====
  stage_row(xb + gyw[0] * WD, w0, t, bufA);
  __syncthreads();
#pragma unroll
  for (int r = 0; r < 8; ++r) {
    unsigned short* cur = (r & 1) ? bufB : bufA;
    unsigned short* nxt = (r & 1) ? bufA : bufB;
    if (r < 7) stage_row(xb + gyw[r + 1] * WD, w0, t, nxt);
    { // head row r: wave wv = M-tile, 3 N-tiles (48 slots, 36 valid)
      const f32x4 zz = {0.f, 0.f, 0.f, 0.f};
#pragma unroll
      for (int nt = 0; nt < 3; ++nt) {
        const int s = (nt << 4) + l15;
        const bf16x8 b0 = *(const bf16x8*)((char*)cur + swz(s, kg * 16));
        const bf16x8 b1 = *(const bf16x8*)((char*)cur + swz(s, 64 + kg * 16));
        f32x4 acc = __builtin_amdgcn_mfma_f32_16x16x32_bf16(ha0, b0, zz, 0, 0, 0);
        acc = __builtin_amdgcn_mfma_f32_16x16x32_bf16(ha1, b1, acc, 0, 0, 0);
        if (s < 36) {
          const float v0 = acc[0] > 0.f ? acc[0] : 0.f;
          const float v1 = acc[1] > 0.f ? acc[1] : 0.f;
          const float v2 = acc[2] > 0.f ? acc[2] : 0.f;
          const float v3 = acc[3] > 0.f ? acc[3] : 0.f;
          uint2 pk2;
          pk2.x = cvt2(v0, v1);
          pk2.y = cvt2(v2, v3);
          *(uint2*)((char*)hl + swz(r * 36 + s, (wv * 16 + kg * 4) * 2)) = pk2;
        }
      }
    }
    __syncthreads();
  }

  // ---- tail A fragments from global Wt (loop-invariant) ----
  bf16x8 ta0, ta1;
  {
    const float* wr = Wt + mrow * 64 + kg * 8;
    ta0 = pack8(*(const float4*)wr, *(const float4*)(wr + 4));
    ta1 = pack8(*(const float4*)(wr + 32), *(const float4*)(wr + 36));
  }

  // ==== NMF + tail per output row q (taps = window rows q, q+2, q+4) ====
  const int px = (wv << 3) | (lane >> 3);   // 0..31
  const int cg16 = (lane & 7) << 4;         // channel-group colbytes

#pragma unroll
  for (int q = 0; q < 4; ++q) {
    // ---- pass 1: 9 b128 tap reads; packed f32x2 accumulation ----
    u32x4 tap[9];
#pragma unroll
    for (int rr = 0; rr < 3; ++rr)
#pragma unroll
      for (int kc = 0; kc < 3; ++kc)
        tap[rr * 3 + kc] =
            *(const u32x4*)((char*)hl + swz((q + 2 * rr) * 36 + px + 2 * kc, cg16));

    f32x2 S2 = {0.f, 0.f};
    f32x2 sumk2[9], A2[9], mreg2[4];
#pragma unroll
    for (int k = 0; k < 9; ++k) { sumk2[k] = (f32x2){0.f, 0.f}; A2[k] = (f32x2){0.f, 0.f}; }
#pragma unroll
    for (int p = 0; p < 4; ++p) {
      f32x2 t2[9];
#pragma unroll
      for (int k = 0; k < 9; ++k) t2[k] = up2(tap[k][p]);
      f32x2 mm = t2[0];
#pragma unroll
      for (int k = 1; k < 9; ++k) mm += t2[k];
      mm *= (1.f / 9.f);
      mreg2[p] = mm;
      S2 += mm * mm;
#pragma unroll
      for (int k = 0; k < 9; ++k) { sumk2[k] += t2[k]; A2[k] += mm * t2[k]; }
    }
    float S = S2[0] + S2[1];
    float sumk[9], A[9];
#pragma unroll
    for (int k = 0; k < 9; ++k) { sumk[k] = sumk2[k][0] + sumk2[k][1]; A[k] = A2[k][0] + A2[k][1]; }

    // ---- butterfly reduce over the 8 channel-group lanes (xor 1,2,4) ----
#pragma unroll
    for (int d = 1; d <= 4; d <<= 1) {
      S += __shfl_xor(S, d);
#pragma unroll
      for (int k = 0; k < 9; ++k) sumk[k] += __shfl_xor(sumk[k], d);
#pragma unroll
      for (int k = 0; k < 9; ++k) A[k] += __shfl_xor(A[k], d);
    }

    float Vk[9], T = 0.f;
#pragma unroll
    for (int k = 0; k < 9; ++k) {
      const float nk = sumk[k] * (1.f / 64.f);
      Vk[k] = nk * A[k] * frcp(3.f * nk * S + EPSV);
      T += Vk[k] * Vk[k];
    }
    const float V4 = Vk[4];

    // ---- pass 2: packed f32x2; fast rcp; b128 UV write ----
    {
      u32x4 uvw;
#pragma unroll
      for (int p = 0; p < 4; ++p) {
        f32x2 B2 = {0.f, 0.f};
#pragma unroll
        for (int k = 0; k < 9; ++k) B2 += up2(tap[k][p]) * Vk[k];
        const f32x2 mm = mreg2[p];
        f32x2 rden;
        rden[0] = frcp(3.f * mm[0] * T + EPSV);
        rden[1] = frcp(3.f * mm[1] * T + EPSV);
        const f32x2 Uc = mm * B2 * rden;
        const f32x2 uvv = 3.f * Uc * V4;
        uvw[p] = cvt2(uvv[0], uvv[1]);
      }
      *(u32x4*)((char*)uvb + swz(px, cg16)) = uvw;   // [px][o]
    }
    __syncthreads();

    // ---- tail MFMA: M-tile wv, N-tiles {0,1}; + residual ----
    const int Y = y0 + q;
    const f32x4 z2 = {0.f, 0.f, 0.f, 0.f};
    const size_t gb = (size_t)b * (NC * HWC) + (size_t)Y * WD + w0;
#pragma unroll
    for (int nt = 0; nt < 2; ++nt) {
      const int pxs = (nt << 4) + l15;
      const bf16x8 b0 = *(const bf16x8*)((char*)uvb + swz(pxs, kg * 16));
      const bf16x8 b1 = *(const bf16x8*)((char*)uvb + swz(pxs, 64 + kg * 16));
      f32x4 acc = __builtin_amdgcn_mfma_f32_16x16x32_bf16(ta0, b0, z2, 0, 0, 0);
      acc = __builtin_amdgcn_mfma_f32_16x16x32_bf16(ta1, b1, acc, 0, 0, 0);
#pragma unroll
      for (int j = 0; j < 4; ++j) {
        const int c2 = (wv << 4) + kg * 4 + j;
        const size_t off = gb + (size_t)c2 * HWC + pxs;
        out[off] = acc[j] + x[off];
      }
    }
    __syncthreads();   // protect uvb for next q
  }
}

extern "C" void kernel_launch(void* const* d_in, const int* in_sizes, int n_in,
                              void* d_out, int out_size, void* d_ws, size_t ws_size,
                              hipStream_t stream) {
  const float* x  = (const float*)d_in[0];
  const float* Wh = (const float*)d_in[1];
  const float* Wt = (const float*)d_in[2];
  float* out = (float*)d_out;

  k_fused<<<512, 256, 0, stream>>>(x, Wh, Wt, out);
}

// Round 20
// 24.566 us; speedup vs baseline: 1.1000x; 1.1000x over previous
//
#include <hip/hip_runtime.h>
#include <hip/hip_bf16.h>

#define HWC 16384      // H*W
#define WD  128
#define NC  64
#define EPSV 1e-6f

typedef __attribute__((ext_vector_type(8))) short bf16x8;
typedef __attribute__((ext_vector_type(4))) float f32x4;
typedef __attribute__((ext_vector_type(2))) float f32x2;
typedef __attribute__((ext_vector_type(4))) unsigned int u32x4;

// f32 pair -> packed bf16 (RNE, v_cvt_pk_bf16_f32)
__device__ __forceinline__ unsigned cvt2(float a, float b) {
  union { __hip_bfloat162 h; unsigned u; } r;
  r.h = __float22bfloat162_rn(make_float2(a, b));
  return r.u;
}
__device__ __forceinline__ float bfLo(unsigned pk) { return __builtin_bit_cast(float, pk << 16); }
__device__ __forceinline__ float bfHi(unsigned pk) { return __builtin_bit_cast(float, pk & 0xFFFF0000u); }
__device__ __forceinline__ f32x2 up2(unsigned w) {
  f32x2 r; r[0] = bfLo(w); r[1] = bfHi(w); return r;
}
// fast reciprocal (v_rcp_f32, ~1 ulp)
__device__ __forceinline__ float frcp(float x) { return __builtin_amdgcn_rcpf(x); }
// XOR swizzle for 128-B-row bf16 tiles.
__device__ __forceinline__ int swz(int row, int colbytes) {
  return ((row << 7) + colbytes) ^ ((row & 7) << 4);
}
__device__ __forceinline__ bf16x8 pack8(float4 a, float4 b) {
  union { unsigned u[4]; bf16x8 v; } r;
  r.u[0] = cvt2(a.x, a.y); r.u[1] = cvt2(a.z, a.w);
  r.u[2] = cvt2(b.x, b.y); r.u[3] = cvt2(b.z, b.w);
  return r.v;
}

// Fully fused head->NMF->tail (R18 structure + residual issue-early).
// 3 barriers; in-wave shfl_xor NMF reduce; packed f32x2 NMF VALU; fast rcp.
// grid 1024 (b,y,seg); 512 thr = 8 waves.
__global__ __launch_bounds__(512) void k_fused(const float* __restrict__ x,
                                               const float* __restrict__ Wh,
                                               const float* __restrict__ Wt,
                                               float* __restrict__ out) {
  __shared__ __align__(16) char smem[53248];
  unsigned short* xt = (unsigned short*)smem;            // [208 sites][64 c], 26624 B
  unsigned short* hl = (unsigned short*)(smem + 26624);  // [208 sites][64 o], 26624 B
  unsigned short* uvb = (unsigned short*)smem;           // overlay on xt (dead after head)

  const int t = threadIdx.x, lane = t & 63, wv = t >> 6;
  const int bid0 = blockIdx.x;
  const int bid = ((bid0 & 7) << 7) | (bid0 >> 3);  // XCD swizzle, bijective (1024%8==0)
  const int seg = bid & 1, y = (bid >> 1) & 127, b = bid >> 8;
  const int w0 = seg << 6;
  const int c0 = wv << 3;
  const int l15 = lane & 15, kg = lane >> 4;
  const int mt = wv & 3;
  const int mrow = (mt << 4) + l15;

  int gy[3];
  gy[0] = y >= 2 ? y - 2 : 0;
  gy[1] = y;
  gy[2] = y <= 125 ? y + 2 : 127;

  const float* xb = x + (size_t)b * (NC * HWC);

  // ---- head A fragments from global Wh (L2-resident) ----
  bf16x8 ha0, ha1;
  {
    const float* wr = Wh + mrow * 64 + kg * 8;
    ha0 = pack8(*(const float4*)wr, *(const float4*)(wr + 4));
    ha1 = pack8(*(const float4*)(wr + 32), *(const float4*)(wr + 36));
  }

  // ---- stage xt[site][ch] (cvt_pk pairs) ----
  {
    int colm = w0 - 2 + lane; if (colm < 0) colm = 0;
#pragma unroll
    for (int r = 0; r < 3; ++r) {
      const float* xr = xb + gy[r] * WD + colm;
      float f[8];
#pragma unroll
      for (int u = 0; u < 8; ++u) f[u] = xr[(size_t)(c0 + u) * HWC];
      u32x4 v;
      v[0] = cvt2(f[0], f[1]); v[1] = cvt2(f[2], f[3]);
      v[2] = cvt2(f[4], f[5]); v[3] = cvt2(f[6], f[7]);
      *(u32x4*)((char*)xt + swz(r * 68 + lane, c0 * 2)) = v;
    }
    if (lane < 12) {   // extra cols i=64..67
      const int re = lane >> 2, e = lane & 3;
      int cole = w0 + 62 + e; if (cole > 127) cole = 127;
      const float* xr = xb + gy[re] * WD + cole;
      float f[8];
#pragma unroll
      for (int u = 0; u < 8; ++u) f[u] = xr[(size_t)(c0 + u) * HWC];
      u32x4 v;
      v[0] = cvt2(f[0], f[1]); v[1] = cvt2(f[2], f[3]);
      v[2] = cvt2(f[4], f[5]); v[3] = cvt2(f[6], f[7]);
      *(u32x4*)((char*)xt + swz(re * 68 + 64 + e, c0 * 2)) = v;
    }
  }
  __syncthreads();   // (1)

  // ---- head MFMA: 13 N-tiles x 4 M-tiles; ReLU; cvt_pk -> hl ----
  {
    const int ntBeg = (wv >> 2) ? 7 : 0;
    const int ntEnd = (wv >> 2) ? 13 : 7;
    const f32x4 z = {0.f, 0.f, 0.f, 0.f};
    for (int nt = ntBeg; nt < ntEnd; ++nt) {
      const int s = (nt << 4) + l15;
      const bf16x8 b0 = *(const bf16x8*)((char*)xt + swz(s, kg * 16));
      const bf16x8 b1 = *(const bf16x8*)((char*)xt + swz(s, 64 + kg * 16));
      f32x4 acc = __builtin_amdgcn_mfma_f32_16x16x32_bf16(ha0, b0, z, 0, 0, 0);
      acc = __builtin_amdgcn_mfma_f32_16x16x32_bf16(ha1, b1, acc, 0, 0, 0);
      const float v0 = acc[0] > 0.f ? acc[0] : 0.f;
      const float v1 = acc[1] > 0.f ? acc[1] : 0.f;
      const float v2 = acc[2] > 0.f ? acc[2] : 0.f;
      const float v3 = acc[3] > 0.f ? acc[3] : 0.f;
      uint2 pk2;
      pk2.x = cvt2(v0, v1);
      pk2.y = cvt2(v2, v3);
      *(uint2*)((char*)hl + swz(s, (mt * 16 + kg * 4) * 2)) = pk2;
    }
  }
  __syncthreads();   // (2)

  // ================= NMF: thread = (px, channel-group cg) =================
  const int px = (wv << 3) | (lane >> 3);   // this thread's pixel
  const int cg16 = (lane & 7) << 4;         // channel-group colbytes (8 ch)

  // ---- pass 1: 9 b128 tap reads; packed f32x2 accumulation ----
  u32x4 tap[9];
#pragma unroll
  for (int r = 0; r < 3; ++r)
#pragma unroll
    for (int kc = 0; kc < 3; ++kc)
      tap[r * 3 + kc] = *(const u32x4*)((char*)hl + swz(r * 68 + px + 2 * kc, cg16));

  f32x2 S2 = {0.f, 0.f};
  f32x2 sumk2[9], A2[9], mreg2[4];
#pragma unroll
  for (int k = 0; k < 9; ++k) { sumk2[k] = (f32x2){0.f, 0.f}; A2[k] = (f32x2){0.f, 0.f}; }
#pragma unroll
  for (int p = 0; p < 4; ++p) {      // channel pair p within this cg
    f32x2 t2[9];
#pragma unroll
    for (int k = 0; k < 9; ++k) t2[k] = up2(tap[k][p]);
    f32x2 mm = t2[0];
#pragma unroll
    for (int k = 1; k < 9; ++k) mm += t2[k];
    mm *= (1.f / 9.f);
    mreg2[p] = mm;
    S2 += mm * mm;
#pragma unroll
    for (int k = 0; k < 9; ++k) { sumk2[k] += t2[k]; A2[k] += mm * t2[k]; }
  }
  float S = S2[0] + S2[1];
  float sumk[9], A[9];
#pragma unroll
  for (int k = 0; k < 9; ++k) { sumk[k] = sumk2[k][0] + sumk2[k][1]; A[k] = A2[k][0] + A2[k][1]; }

  // ---- butterfly reduce over the 8 channel-group lanes (xor 1,2,4) ----
#pragma unroll
  for (int d = 1; d <= 4; d <<= 1) {
    S += __shfl_xor(S, d);
#pragma unroll
    for (int k = 0; k < 9; ++k) sumk[k] += __shfl_xor(sumk[k], d);
#pragma unroll
    for (int k = 0; k < 9; ++k) A[k] += __shfl_xor(A[k], d);
  }

  float Vk[9], T = 0.f;
#pragma unroll
  for (int k = 0; k < 9; ++k) {
    const float nk = sumk[k] * (1.f / 64.f);
    Vk[k] = nk * A[k] * frcp(3.f * nk * S + EPSV);   // fast rcp
    T += Vk[k] * Vk[k];
  }
  const float V4 = Vk[4];

  // ---- tail A fragments from global Wt (hides under pass 2) ----
  bf16x8 ta0, ta1;
  {
    const float* wr = Wt + mrow * 64 + kg * 8;
    ta0 = pack8(*(const float4*)wr, *(const float4*)(wr + 4));
    ta1 = pack8(*(const float4*)(wr + 32), *(const float4*)(wr + 36));
  }

  // ---- pass 2: packed f32x2 from cached taps; fast rcp; b128 UV write ----
  {
    u32x4 uvw;
#pragma unroll
    for (int p = 0; p < 4; ++p) {
      f32x2 B2 = {0.f, 0.f};
#pragma unroll
      for (int k = 0; k < 9; ++k) B2 += up2(tap[k][p]) * Vk[k];
      const f32x2 mm = mreg2[p];
      f32x2 rden;
      rden[0] = frcp(3.f * mm[0] * T + EPSV);
      rden[1] = frcp(3.f * mm[1] * T + EPSV);
      const f32x2 Uc = mm * B2 * rden;
      const f32x2 uvv = 3.f * Uc * V4;
      uvw[p] = cvt2(uvv[0], uvv[1]);
    }
    *(u32x4*)((char*)uvb + swz(px, cg16)) = uvw;   // [px][o]
  }

  // ---- residual issue-early (T14): loads fly across barrier (3), land in tail ----
  const int n0 = (wv >> 2) << 1;
  const size_t gb = (size_t)b * (NC * HWC) + (size_t)y * WD + w0;
  float resv[2][4];
#pragma unroll
  for (int q = 0; q < 2; ++q) {
    const int pxs = ((n0 + q) << 4) + l15;
#pragma unroll
    for (int j = 0; j < 4; ++j)
      resv[q][j] = x[gb + (size_t)((mt << 4) + kg * 4 + j) * HWC + pxs];
  }
  __syncthreads();   // (3)

  // ---- tail MFMA: M-tile mt, N-tiles {n0, n0+1}; + prefetched residual ----
  const f32x4 z2 = {0.f, 0.f, 0.f, 0.f};
#pragma unroll
  for (int q = 0; q < 2; ++q) {
    const int pxs = ((n0 + q) << 4) + l15;
    const bf16x8 b0 = *(const bf16x8*)((char*)uvb + swz(pxs, kg * 16));
    const bf16x8 b1 = *(const bf16x8*)((char*)uvb + swz(pxs, 64 + kg * 16));
    f32x4 acc = __builtin_amdgcn_mfma_f32_16x16x32_bf16(ta0, b0, z2, 0, 0, 0);
    acc = __builtin_amdgcn_mfma_f32_16x16x32_bf16(ta1, b1, acc, 0, 0, 0);
#pragma unroll
    for (int j = 0; j < 4; ++j) {
      const int c2 = (mt << 4) + kg * 4 + j;
      const size_t off = gb + (size_t)c2 * HWC + pxs;
      out[off] = acc[j] + resv[q][j];
    }
  }
}

extern "C" void kernel_launch(void* const* d_in, const int* in_sizes, int n_in,
                              void* d_out, int out_size, void* d_ws, size_t ws_size,
                              hipStream_t stream) {
  const float* x  = (const float*)d_in[0];
  const float* Wh = (const float*)d_in[1];
  const float* Wt = (const float*)d_in[2];
  float* out = (float*)d_out;

  k_fused<<<1024, 512, 0, stream>>>(x, Wh, Wt, out);
}

// Round 21
// 24.168 us; speedup vs baseline: 1.1181x; 1.0165x over previous
//
#include <hip/hip_runtime.h>
#include <hip/hip_bf16.h>

#define HWC 16384      // H*W
#define WD  128
#define NC  64
#define EPSV 1e-6f

typedef __attribute__((ext_vector_type(8))) short bf16x8;
typedef __attribute__((ext_vector_type(4))) float f32x4;
typedef __attribute__((ext_vector_type(2))) float f32x2;
typedef __attribute__((ext_vector_type(4))) unsigned int u32x4;

// f32 pair -> packed bf16 (RNE, v_cvt_pk_bf16_f32)
__device__ __forceinline__ unsigned cvt2(float a, float b) {
  union { __hip_bfloat162 h; unsigned u; } r;
  r.h = __float22bfloat162_rn(make_float2(a, b));
  return r.u;
}
__device__ __forceinline__ float bfLo(unsigned pk) { return __builtin_bit_cast(float, pk << 16); }
__device__ __forceinline__ float bfHi(unsigned pk) { return __builtin_bit_cast(float, pk & 0xFFFF0000u); }
__device__ __forceinline__ f32x2 up2(unsigned w) {
  f32x2 r; r[0] = bfLo(w); r[1] = bfHi(w); return r;
}
// fast reciprocal (v_rcp_f32, ~1 ulp) — absmax headroom is 3x, error ~1e-7
__device__ __forceinline__ float frcp(float x) { return __builtin_amdgcn_rcpf(x); }
// XOR swizzle for 128-B-row bf16 tiles.
__device__ __forceinline__ int swz(int row, int colbytes) {
  return ((row << 7) + colbytes) ^ ((row & 7) << 4);
}
__device__ __forceinline__ bf16x8 pack8(float4 a, float4 b) {
  union { unsigned u[4]; bf16x8 v; } r;
  r.u[0] = cvt2(a.x, a.y); r.u[1] = cvt2(a.z, a.w);
  r.u[2] = cvt2(b.x, b.y); r.u[3] = cvt2(b.z, b.w);
  return r.v;
}

// Fully fused head->NMF->tail. 3 barriers; in-wave shfl_xor NMF reduce;
// packed f32x2 NMF VALU; fast-rcp for all divisions.
// grid 1024 (b,y,seg); 512 thr = 8 waves.  [R18 measured-best: 24.1 us]
__global__ __launch_bounds__(512) void k_fused(const float* __restrict__ x,
                                               const float* __restrict__ Wh,
                                               const float* __restrict__ Wt,
                                               float* __restrict__ out) {
  __shared__ __align__(16) char smem[53248];
  unsigned short* xt = (unsigned short*)smem;            // [208 sites][64 c], 26624 B
  unsigned short* hl = (unsigned short*)(smem + 26624);  // [208 sites][64 o], 26624 B
  unsigned short* uvb = (unsigned short*)smem;           // overlay on xt (dead after head)

  const int t = threadIdx.x, lane = t & 63, wv = t >> 6;
  const int bid0 = blockIdx.x;
  const int bid = ((bid0 & 7) << 7) | (bid0 >> 3);  // XCD swizzle, bijective (1024%8==0)
  const int seg = bid & 1, y = (bid >> 1) & 127, b = bid >> 8;
  const int w0 = seg << 6;
  const int c0 = wv << 3;
  const int l15 = lane & 15, kg = lane >> 4;
  const int mt = wv & 3;
  const int mrow = (mt << 4) + l15;

  int gy[3];
  gy[0] = y >= 2 ? y - 2 : 0;
  gy[1] = y;
  gy[2] = y <= 125 ? y + 2 : 127;

  const float* xb = x + (size_t)b * (NC * HWC);

  // ---- head A fragments from global Wh (L2-resident) ----
  bf16x8 ha0, ha1;
  {
    const float* wr = Wh + mrow * 64 + kg * 8;
    ha0 = pack8(*(const float4*)wr, *(const float4*)(wr + 4));
    ha1 = pack8(*(const float4*)(wr + 32), *(const float4*)(wr + 36));
  }

  // ---- stage xt[site][ch] (cvt_pk pairs) ----
  {
    int colm = w0 - 2 + lane; if (colm < 0) colm = 0;
#pragma unroll
    for (int r = 0; r < 3; ++r) {
      const float* xr = xb + gy[r] * WD + colm;
      float f[8];
#pragma unroll
      for (int u = 0; u < 8; ++u) f[u] = xr[(size_t)(c0 + u) * HWC];
      u32x4 v;
      v[0] = cvt2(f[0], f[1]); v[1] = cvt2(f[2], f[3]);
      v[2] = cvt2(f[4], f[5]); v[3] = cvt2(f[6], f[7]);
      *(u32x4*)((char*)xt + swz(r * 68 + lane, c0 * 2)) = v;
    }
    if (lane < 12) {   // extra cols i=64..67
      const int re = lane >> 2, e = lane & 3;
      int cole = w0 + 62 + e; if (cole > 127) cole = 127;
      const float* xr = xb + gy[re] * WD + cole;
      float f[8];
#pragma unroll
      for (int u = 0; u < 8; ++u) f[u] = xr[(size_t)(c0 + u) * HWC];
      u32x4 v;
      v[0] = cvt2(f[0], f[1]); v[1] = cvt2(f[2], f[3]);
      v[2] = cvt2(f[4], f[5]); v[3] = cvt2(f[6], f[7]);
      *(u32x4*)((char*)xt + swz(re * 68 + 64 + e, c0 * 2)) = v;
    }
  }
  __syncthreads();   // (1)

  // ---- head MFMA: 13 N-tiles x 4 M-tiles; ReLU; cvt_pk -> hl ----
  {
    const int ntBeg = (wv >> 2) ? 7 : 0;
    const int ntEnd = (wv >> 2) ? 13 : 7;
    const f32x4 z = {0.f, 0.f, 0.f, 0.f};
    for (int nt = ntBeg; nt < ntEnd; ++nt) {
      const int s = (nt << 4) + l15;
      const bf16x8 b0 = *(const bf16x8*)((char*)xt + swz(s, kg * 16));
      const bf16x8 b1 = *(const bf16x8*)((char*)xt + swz(s, 64 + kg * 16));
      f32x4 acc = __builtin_amdgcn_mfma_f32_16x16x32_bf16(ha0, b0, z, 0, 0, 0);
      acc = __builtin_amdgcn_mfma_f32_16x16x32_bf16(ha1, b1, acc, 0, 0, 0);
      const float v0 = acc[0] > 0.f ? acc[0] : 0.f;
      const float v1 = acc[1] > 0.f ? acc[1] : 0.f;
      const float v2 = acc[2] > 0.f ? acc[2] : 0.f;
      const float v3 = acc[3] > 0.f ? acc[3] : 0.f;
      uint2 pk2;
      pk2.x = cvt2(v0, v1);
      pk2.y = cvt2(v2, v3);
      *(uint2*)((char*)hl + swz(s, (mt * 16 + kg * 4) * 2)) = pk2;
    }
  }
  __syncthreads();   // (2)

  // ================= NMF: thread = (px, channel-group cg) =================
  const int px = (wv << 3) | (lane >> 3);   // this thread's pixel
  const int cg16 = (lane & 7) << 4;         // channel-group colbytes (8 ch)

  // ---- pass 1: 9 b128 tap reads; packed f32x2 accumulation ----
  u32x4 tap[9];
#pragma unroll
  for (int r = 0; r < 3; ++r)
#pragma unroll
    for (int kc = 0; kc < 3; ++kc)
      tap[r * 3 + kc] = *(const u32x4*)((char*)hl + swz(r * 68 + px + 2 * kc, cg16));

  f32x2 S2 = {0.f, 0.f};
  f32x2 sumk2[9], A2[9], mreg2[4];
#pragma unroll
  for (int k = 0; k < 9; ++k) { sumk2[k] = (f32x2){0.f, 0.f}; A2[k] = (f32x2){0.f, 0.f}; }
#pragma unroll
  for (int p = 0; p < 4; ++p) {      // channel pair p within this cg
    f32x2 t2[9];
#pragma unroll
    for (int k = 0; k < 9; ++k) t2[k] = up2(tap[k][p]);
    f32x2 mm = t2[0];
#pragma unroll
    for (int k = 1; k < 9; ++k) mm += t2[k];
    mm *= (1.f / 9.f);
    mreg2[p] = mm;
    S2 += mm * mm;
#pragma unroll
    for (int k = 0; k < 9; ++k) { sumk2[k] += t2[k]; A2[k] += mm * t2[k]; }
  }
  float S = S2[0] + S2[1];
  float sumk[9], A[9];
#pragma unroll
  for (int k = 0; k < 9; ++k) { sumk[k] = sumk2[k][0] + sumk2[k][1]; A[k] = A2[k][0] + A2[k][1]; }

  // ---- butterfly reduce over the 8 channel-group lanes (xor 1,2,4) ----
#pragma unroll
  for (int d = 1; d <= 4; d <<= 1) {
    S += __shfl_xor(S, d);
#pragma unroll
    for (int k = 0; k < 9; ++k) sumk[k] += __shfl_xor(sumk[k], d);
#pragma unroll
    for (int k = 0; k < 9; ++k) A[k] += __shfl_xor(A[k], d);
  }

  float Vk[9], T = 0.f;
#pragma unroll
  for (int k = 0; k < 9; ++k) {
    const float nk = sumk[k] * (1.f / 64.f);
    Vk[k] = nk * A[k] * frcp(3.f * nk * S + EPSV);   // fast rcp
    T += Vk[k] * Vk[k];
  }
  const float V4 = Vk[4];

  // ---- tail A fragments from global Wt (hides under pass 2) ----
  bf16x8 ta0, ta1;
  {
    const float* wr = Wt + mrow * 64 + kg * 8;
    ta0 = pack8(*(const float4*)wr, *(const float4*)(wr + 4));
    ta1 = pack8(*(const float4*)(wr + 32), *(const float4*)(wr + 36));
  }

  // ---- pass 2: packed f32x2 from cached taps; fast rcp; b128 UV write ----
  {
    u32x4 uvw;
#pragma unroll
    for (int p = 0; p < 4; ++p) {
      f32x2 B2 = {0.f, 0.f};
#pragma unroll
      for (int k = 0; k < 9; ++k) B2 += up2(tap[k][p]) * Vk[k];
      const f32x2 mm = mreg2[p];
      f32x2 rden;
      rden[0] = frcp(3.f * mm[0] * T + EPSV);
      rden[1] = frcp(3.f * mm[1] * T + EPSV);
      const f32x2 Uc = mm * B2 * rden;
      const f32x2 uvv = 3.f * Uc * V4;
      uvw[p] = cvt2(uvv[0], uvv[1]);
    }
    *(u32x4*)((char*)uvb + swz(px, cg16)) = uvw;   // [px][o]
  }
  __syncthreads();   // (3)

  // ---- tail MFMA: M-tile mt, N-tiles {2*(wv>>2), +1}; + residual ----
  const int n0 = (wv >> 2) << 1;
  const f32x4 z2 = {0.f, 0.f, 0.f, 0.f};
  const size_t gb = (size_t)b * (NC * HWC) + (size_t)y * WD + w0;
#pragma unroll
  for (int nt = n0; nt < n0 + 2; ++nt) {
    const int pxs = (nt << 4) + l15;
    const bf16x8 b0 = *(const bf16x8*)((char*)uvb + swz(pxs, kg * 16));
    const bf16x8 b1 = *(const bf16x8*)((char*)uvb + swz(pxs, 64 + kg * 16));
    f32x4 acc = __builtin_amdgcn_mfma_f32_16x16x32_bf16(ta0, b0, z2, 0, 0, 0);
    acc = __builtin_amdgcn_mfma_f32_16x16x32_bf16(ta1, b1, acc, 0, 0, 0);
#pragma unroll
    for (int j = 0; j < 4; ++j) {
      const int c2 = (mt << 4) + kg * 4 + j;
      const size_t off = gb + (size_t)c2 * HWC + pxs;
      out[off] = acc[j] + x[off];
    }
  }
}

extern "C" void kernel_launch(void* const* d_in, const int* in_sizes, int n_in,
                              void* d_out, int out_size, void* d_ws, size_t ws_size,
                              hipStream_t stream) {
  const float* x  = (const float*)d_in[0];
  const float* Wh = (const float*)d_in[1];
  const float* Wt = (const float*)d_in[2];
  float* out = (float*)d_out;

  k_fused<<<1024, 512, 0, stream>>>(x, Wh, Wt, out);
}